// Round 1
// baseline (1462.714 us; speedup 1.0000x reference)
//
#include <hip/hip_runtime.h>
#include <math.h>

#define HW 262144     // 512*512
#define NIMG 96       // B*C
#define NQBIN 4096
#define BM 128
#define BN 128
#define BK 16

// ---- monotone float<->uint map for radix select ----
__device__ __forceinline__ unsigned fmap_u(float f){
  unsigned u = __float_as_uint(f);
  return (u & 0x80000000u) ? ~u : (u | 0x80000000u);
}
__device__ __forceinline__ float funmap_u(unsigned u){
  unsigned v = (u & 0x80000000u) ? (u & 0x7fffffffu) : ~u;
  return __uint_as_float(v);
}

// ---- Dir[n] = Re( ifft(filter_map row 0) )[n], computed in double ----
__global__ void k_dir(const float* __restrict__ fmap_in, float* __restrict__ Dir){
  int n = blockIdx.x;          // 0..511
  int t = threadIdx.x;         // 256 threads
  double s = 0.0;
  for(int c = t; c < 512; c += 256){
    int a = (c * n) & 511;     // periodicity keeps the angle small
    s += (double)fmap_in[c] * cos(6.283185307179586476925287 * (double)a / 512.0);
  }
  __shared__ double red[256];
  red[t] = s; __syncthreads();
  for(int off = 128; off; off >>= 1){
    if(t < off) red[t] += red[t + off];
    __syncthreads();
  }
  if(t == 0) Dir[n] = (float)(red[0] / 512.0);
}

// ---- median pass 1: histogram of high 16 bits of mapped value ----
__global__ void k_hist1(const float* __restrict__ x, unsigned* __restrict__ hist){
  const int img  = blockIdx.x >> 3;
  const int part = blockIdx.x & 7;
  const float4* p = (const float4*)(x + (size_t)img * HW + (size_t)part * 32768);
  unsigned* h = hist + (size_t)img * 65536;
  for(int i = threadIdx.x; i < 8192; i += 256){
    float4 v = p[i];
    atomicAdd(&h[fmap_u(v.x) >> 16], 1u);
    atomicAdd(&h[fmap_u(v.y) >> 16], 1u);
    atomicAdd(&h[fmap_u(v.z) >> 16], 1u);
    atomicAdd(&h[fmap_u(v.w) >> 16], 1u);
  }
}

// find bin containing order stat 131071; store (bin, residual rank)
__global__ void k_scan1(const unsigned* __restrict__ hist, uint2* __restrict__ sel){
  int img = blockIdx.x;
  const unsigned* h = hist + (size_t)img * 65536;
  __shared__ unsigned csum[256];
  int t = threadIdx.x;
  unsigned s = 0;
  for(int j = 0; j < 256; j++) s += h[t * 256 + j];
  csum[t] = s; __syncthreads();
  if(t == 0){
    unsigned k = 131071u, cum = 0; int chunk = 0;
    for(; chunk < 256; ++chunk){ if(cum + csum[chunk] > k) break; cum += csum[chunk]; }
    int b = chunk * 256;
    for(;; ++b){ unsigned c = h[b]; if(cum + c > k) break; cum += c; }
    sel[img] = make_uint2((unsigned)b, k - cum);
  }
}

// ---- median pass 2: histogram low 16 bits among elements matching high-16 bin ----
__global__ void k_hist2(const float* __restrict__ x, const uint2* __restrict__ sel,
                        unsigned* __restrict__ hist){
  const int img  = blockIdx.x >> 3;
  const int part = blockIdx.x & 7;
  const unsigned h16 = sel[img].x;
  const float4* p = (const float4*)(x + (size_t)img * HW + (size_t)part * 32768);
  unsigned* h = hist + (size_t)img * 65536;
  for(int i = threadIdx.x; i < 8192; i += 256){
    float4 v = p[i];
    unsigned u;
    u = fmap_u(v.x); if((u >> 16) == h16) atomicAdd(&h[u & 0xFFFFu], 1u);
    u = fmap_u(v.y); if((u >> 16) == h16) atomicAdd(&h[u & 0xFFFFu], 1u);
    u = fmap_u(v.z); if((u >> 16) == h16) atomicAdd(&h[u & 0xFFFFu], 1u);
    u = fmap_u(v.w); if((u >> 16) == h16) atomicAdd(&h[u & 0xFFFFu], 1u);
  }
}

__global__ void k_scan2(const unsigned* __restrict__ hist, const uint2* __restrict__ sel,
                        float* __restrict__ med){
  int img = blockIdx.x;
  const unsigned* h = hist + (size_t)img * 65536;
  __shared__ unsigned csum[256];
  int t = threadIdx.x;
  unsigned s = 0;
  for(int j = 0; j < 256; j++) s += h[t * 256 + j];
  csum[t] = s; __syncthreads();
  if(t == 0){
    unsigned k = sel[img].y, cum = 0; int chunk = 0;
    for(; chunk < 256; ++chunk){ if(cum + csum[chunk] > k) break; cum += csum[chunk]; }
    int b = chunk * 256;
    for(;; ++b){ unsigned c = h[b]; if(cum + c > k) break; cum += c; }
    med[img] = funmap_u((sel[img].x << 16) | (unsigned)b) + 0.2f;
  }
}

// ---- row pass: t1[r][n] = sum_k padded[r][k] * Dir[(n-k)&511] ----
__global__ __launch_bounds__(256) void k_rowpass(
    const float* __restrict__ x, const float* __restrict__ mask,
    const float* __restrict__ med, const float* __restrict__ Dir,
    float* __restrict__ t1)
{
  __shared__ alignas(16) float As[BK][BM];
  __shared__ alignas(16) float Bs[BK][BN];
  __shared__ float DirS[512];
  const int t  = threadIdx.x;
  const int n0 = blockIdx.x * BN;
  const int r0 = blockIdx.y * BM;
  const int bc = r0 >> 9;
  const int bb = bc / 3;
  const int h0 = r0 & 511;
  const float mv = med[bc];

  for(int i = t; i < 512; i += 256) DirS[i] = Dir[i];

  const int lr = t >> 2;
  const int lk = (t & 3) << 2;
  const int bn = (t & 31) << 2;
  const int bk = t >> 5;
  const int tx = t & 15, ty = t >> 4;

  float acc[8][8];
  #pragma unroll
  for(int i = 0; i < 8; i++)
    #pragma unroll
    for(int j = 0; j < 8; j++) acc[i][j] = 0.f;

  __syncthreads();

  for(int k0 = 0; k0 < 512; k0 += BK){
    #pragma unroll
    for(int p = 0; p < 2; p++){
      int row = lr + p * 64;
      const float4 xv = *(const float4*)(x    + (size_t)(r0 + row) * 512 + k0 + lk);
      const float4 mk = *(const float4*)(mask + (size_t)bb * HW + (size_t)(h0 + row) * 512 + k0 + lk);
      As[lk + 0][row] = (mk.x != 0.f) ? xv.x : mv;
      As[lk + 1][row] = (mk.y != 0.f) ? xv.y : mv;
      As[lk + 2][row] = (mk.z != 0.f) ? xv.z : mv;
      As[lk + 3][row] = (mk.w != 0.f) ? xv.w : mv;
    }
    #pragma unroll
    for(int p = 0; p < 2; p++){
      int kk = bk + p * 8;
      #pragma unroll
      for(int j = 0; j < 4; j++)
        Bs[kk][bn + j] = DirS[(n0 + bn + j - k0 - kk) & 511];
    }
    __syncthreads();
    #pragma unroll
    for(int k = 0; k < BK; k++){
      float4 a0 = *(const float4*)&As[k][ty * 8];
      float4 a1 = *(const float4*)&As[k][ty * 8 + 4];
      float4 b0 = *(const float4*)&Bs[k][tx * 8];
      float4 b1 = *(const float4*)&Bs[k][tx * 8 + 4];
      float av[8] = {a0.x,a0.y,a0.z,a0.w,a1.x,a1.y,a1.z,a1.w};
      float bv[8] = {b0.x,b0.y,b0.z,b0.w,b1.x,b1.y,b1.z,b1.w};
      #pragma unroll
      for(int i = 0; i < 8; i++)
        #pragma unroll
        for(int j = 0; j < 8; j++)
          acc[i][j] = fmaf(av[i], bv[j], acc[i][j]);
    }
    __syncthreads();
  }
  #pragma unroll
  for(int i = 0; i < 8; i++){
    float* dst = t1 + (size_t)(r0 + ty * 8 + i) * 512 + n0 + tx * 8;
    *(float4*)dst       = make_float4(acc[i][0], acc[i][1], acc[i][2], acc[i][3]);
    *(float4*)(dst + 4) = make_float4(acc[i][4], acc[i][5], acc[i][6], acc[i][7]);
  }
}

// ---- col pass: res[h'][w] = | sum_h Dir[(h-h')&511] * t1[h][w] | ----
__global__ __launch_bounds__(256) void k_colpass(
    const float* __restrict__ t1, const float* __restrict__ Dir,
    float* __restrict__ res)
{
  __shared__ alignas(16) float As[BK][BM];
  __shared__ alignas(16) float Bs[BK][BN];
  __shared__ float DirS[512];
  const int t   = threadIdx.x;
  const int w0  = blockIdx.x * BN;
  const int hp0 = blockIdx.y * BM;
  const int img = blockIdx.z;
  const float* timg = t1 + (size_t)img * HW;

  for(int i = t; i < 512; i += 256) DirS[i] = Dir[i];

  const int lr = t >> 2;
  const int lk = (t & 3) << 2;
  const int bn = (t & 31) << 2;
  const int bk = t >> 5;
  const int tx = t & 15, ty = t >> 4;

  float acc[8][8];
  #pragma unroll
  for(int i = 0; i < 8; i++)
    #pragma unroll
    for(int j = 0; j < 8; j++) acc[i][j] = 0.f;

  __syncthreads();

  for(int k0 = 0; k0 < 512; k0 += BK){
    #pragma unroll
    for(int p = 0; p < 2; p++){
      int row = lr + p * 64;
      #pragma unroll
      for(int j = 0; j < 4; j++)
        As[lk + j][row] = DirS[(k0 + lk + j - hp0 - row) & 511];
    }
    #pragma unroll
    for(int p = 0; p < 2; p++){
      int kk = bk + p * 8;
      *(float4*)&Bs[kk][bn] = *(const float4*)(timg + (size_t)(k0 + kk) * 512 + w0 + bn);
    }
    __syncthreads();
    #pragma unroll
    for(int k = 0; k < BK; k++){
      float4 a0 = *(const float4*)&As[k][ty * 8];
      float4 a1 = *(const float4*)&As[k][ty * 8 + 4];
      float4 b0 = *(const float4*)&Bs[k][tx * 8];
      float4 b1 = *(const float4*)&Bs[k][tx * 8 + 4];
      float av[8] = {a0.x,a0.y,a0.z,a0.w,a1.x,a1.y,a1.z,a1.w};
      float bv[8] = {b0.x,b0.y,b0.z,b0.w,b1.x,b1.y,b1.z,b1.w};
      #pragma unroll
      for(int i = 0; i < 8; i++)
        #pragma unroll
        for(int j = 0; j < 8; j++)
          acc[i][j] = fmaf(av[i], bv[j], acc[i][j]);
    }
    __syncthreads();
  }
  #pragma unroll
  for(int i = 0; i < 8; i++){
    float* dst = res + (size_t)img * HW + (size_t)(hp0 + ty * 8 + i) * 512 + w0 + tx * 8;
    *(float4*)dst       = make_float4(fabsf(acc[i][0]), fabsf(acc[i][1]), fabsf(acc[i][2]), fabsf(acc[i][3]));
    *(float4*)(dst + 4) = make_float4(fabsf(acc[i][4]), fabsf(acc[i][5]), fabsf(acc[i][6]), fabsf(acc[i][7]));
  }
}

// ---- histogram of q = trunc(res*256) (exact order statistics of quantized values) ----
__global__ __launch_bounds__(256) void k_qhist(const float* __restrict__ res, unsigned* __restrict__ qh){
  __shared__ unsigned sh[NQBIN];
  const int img  = blockIdx.x >> 3;
  const int part = blockIdx.x & 7;
  const float4* p = (const float4*)(res + (size_t)img * HW + (size_t)part * 32768);
  for(int i = threadIdx.x; i < NQBIN; i += 256) sh[i] = 0;
  __syncthreads();
  for(int i = threadIdx.x; i < 8192; i += 256){
    float4 v = p[i];
    int b0 = min((int)(v.x * 256.f), NQBIN - 1);
    int b1 = min((int)(v.y * 256.f), NQBIN - 1);
    int b2 = min((int)(v.z * 256.f), NQBIN - 1);
    int b3 = min((int)(v.w * 256.f), NQBIN - 1);
    atomicAdd(&sh[b0], 1u); atomicAdd(&sh[b1], 1u);
    atomicAdd(&sh[b2], 1u); atomicAdd(&sh[b3], 1u);
  }
  __syncthreads();
  unsigned* h = qh + (size_t)img * NQBIN;
  for(int i = threadIdx.x; i < NQBIN; i += 256){
    unsigned c = sh[i];
    if(c) atomicAdd(&h[i], c);
  }
}

// ---- percentiles (linear interp at 3% / 97%) -> (lo, 1/(hi-lo)) ----
__global__ void k_pct(const unsigned* __restrict__ qh, float2* __restrict__ prm){
  int img = blockIdx.x, t = threadIdx.x;
  const unsigned* h = qh + (size_t)img * NQBIN;
  __shared__ unsigned sh[NQBIN];
  for(int i = t; i < NQBIN; i += 256) sh[i] = h[i];
  __syncthreads();
  if(t == 0){
    const unsigned targ[4] = {7864u, 7865u, 254278u, 254279u};
    float v[4]; unsigned cum = 0; int b = 0;
    for(int q = 0; q < 4; q++){
      while(cum + sh[b] <= targ[q]){ cum += sh[b]; ++b; }
      v[q] = (float)b * (1.0f / 256.0f);
    }
    double plo = 0.03 * 262143.0;   // 7864.29
    double phi = 0.97 * 262143.0;   // 254278.71
    float lo = v[0] + (float)(plo - 7864.0)   * (v[1] - v[0]);
    float hi = v[2] + (float)(phi - 254278.0) * (v[3] - v[2]);
    prm[img] = make_float2(lo, 1.0f / (hi - lo));
  }
}

// ---- in-place normalize: out = (res - lo) * inv * mask ----
__global__ __launch_bounds__(256) void k_norm(float* __restrict__ out, const float* __restrict__ mask,
                                              const float2* __restrict__ prm){
  size_t i4 = (size_t)blockIdx.x * blockDim.x + threadIdx.x;
  const size_t total4 = (size_t)NIMG * HW / 4;
  const size_t step = (size_t)gridDim.x * blockDim.x;
  for(; i4 < total4; i4 += step){
    size_t i = i4 * 4;
    int bc = (int)(i >> 18);
    int bb = bc / 3;
    size_t mi = ((size_t)bb << 18) + (i & 0x3FFFFu);
    float4 r = *(float4*)(out + i);
    float4 m = *(const float4*)(mask + mi);
    float2 p = prm[bc];
    float4 o;
    o.x = (r.x - p.x) * p.y * m.x;
    o.y = (r.y - p.x) * p.y * m.y;
    o.z = (r.z - p.x) * p.y * m.z;
    o.w = (r.w - p.x) * p.y * m.w;
    *(float4*)(out + i) = o;
  }
}

extern "C" void kernel_launch(void* const* d_in, const int* in_sizes, int n_in,
                              void* d_out, int out_size, void* d_ws, size_t ws_size,
                              hipStream_t stream)
{
  const float* x       = (const float*)d_in[0];
  const float* mask    = (const float*)d_in[1];
  const float* fmap_in = (const float*)d_in[2];
  float* out = (float*)d_out;

  const size_t T1_BYTES = (size_t)NIMG * HW * 4;   // 100663296
  char* ws = (char*)d_ws;
  float*    t1     = (float*)ws;           // lives steps rowpass..colpass
  unsigned* hist16 = (unsigned*)ws;        // alias: used before t1 is written (24 MB)
  unsigned* qhist  = (unsigned*)ws;        // alias: used after t1 is dead (1.5 MB)
  char* tail = ws + T1_BYTES;
  float*  Dir = (float*)tail;              // 2048 B
  float*  med = (float*)(tail + 2048);     // 384 B (padded to 512)
  uint2*  sel = (uint2*)(tail + 2560);     // 768 B
  float2* prm = (float2*)(tail + 3328);    // 768 B

  k_dir<<<512, 256, 0, stream>>>(fmap_in, Dir);

  hipMemsetAsync(hist16, 0, (size_t)NIMG * 65536 * 4, stream);
  k_hist1<<<NIMG * 8, 256, 0, stream>>>(x, hist16);
  k_scan1<<<NIMG, 256, 0, stream>>>(hist16, sel);
  hipMemsetAsync(hist16, 0, (size_t)NIMG * 65536 * 4, stream);
  k_hist2<<<NIMG * 8, 256, 0, stream>>>(x, sel, hist16);
  k_scan2<<<NIMG, 256, 0, stream>>>(hist16, sel, med);

  k_rowpass<<<dim3(512 / BN, (NIMG * 512) / BM), 256, 0, stream>>>(x, mask, med, Dir, t1);
  k_colpass<<<dim3(512 / BN, 512 / BM, NIMG), 256, 0, stream>>>(t1, Dir, out);

  hipMemsetAsync(qhist, 0, (size_t)NIMG * NQBIN * 4, stream);
  k_qhist<<<NIMG * 8, 256, 0, stream>>>(out, qhist);
  k_pct<<<NIMG, 256, 0, stream>>>(qhist, prm);
  k_norm<<<2048, 256, 0, stream>>>(out, mask, prm);
}

// Round 2
// 782.182 us; speedup vs baseline: 1.8700x; 1.8700x over previous
//
#include <hip/hip_runtime.h>
#include <math.h>

#define HW 262144     // 512*512
#define NIMG 96       // B*C
#define NQBIN 4096
#define BM 128
#define BN 128
#define BK 16

// ---- monotone float<->uint map for radix select ----
__device__ __forceinline__ unsigned fmap_u(float f){
  unsigned u = __float_as_uint(f);
  return (u & 0x80000000u) ? ~u : (u | 0x80000000u);
}
__device__ __forceinline__ float funmap_u(unsigned u){
  unsigned v = (u & 0x80000000u) ? (u & 0x7fffffffu) : ~u;
  return __uint_as_float(v);
}

// ---- Dir[n] = Re( ifft(filter_map row 0) )[n], computed in double ----
__global__ void k_dir(const float* __restrict__ fmap_in, float* __restrict__ Dir){
  int n = blockIdx.x;          // 0..511
  int t = threadIdx.x;         // 256 threads
  double s = 0.0;
  for(int c = t; c < 512; c += 256){
    int a = (c * n) & 511;     // periodicity keeps the angle small
    s += (double)fmap_in[c] * cos(6.283185307179586476925287 * (double)a / 512.0);
  }
  __shared__ double red[256];
  red[t] = s; __syncthreads();
  for(int off = 128; off; off >>= 1){
    if(t < off) red[t] += red[t + off];
    __syncthreads();
  }
  if(t == 0) Dir[n] = (float)(red[0] / 512.0);
}

// ==== exact median via 3-pass LDS radix select (12 / 12 / 8 bits) ====

// pass 1: histogram of top 12 bits (LDS-private, merged to global)
__global__ __launch_bounds__(256) void k_p1(const float* __restrict__ x, unsigned* __restrict__ h){
  __shared__ unsigned sh[4096];
  const int img  = blockIdx.x >> 3;
  const int part = blockIdx.x & 7;
  const float4* p = (const float4*)(x + (size_t)img * HW + (size_t)part * 32768);
  for(int i = threadIdx.x; i < 4096; i += 256) sh[i] = 0;
  __syncthreads();
  for(int i = threadIdx.x; i < 8192; i += 256){
    float4 v = p[i];
    atomicAdd(&sh[fmap_u(v.x) >> 20], 1u);
    atomicAdd(&sh[fmap_u(v.y) >> 20], 1u);
    atomicAdd(&sh[fmap_u(v.z) >> 20], 1u);
    atomicAdd(&sh[fmap_u(v.w) >> 20], 1u);
  }
  __syncthreads();
  unsigned* hh = h + (size_t)img * 4096;
  for(int i = threadIdx.x; i < 4096; i += 256){
    unsigned c = sh[i];
    if(c) atomicAdd(&hh[i], c);
  }
}

// pass 2: among elements whose top-12 matches sel1, histogram bits [19:8]
__global__ __launch_bounds__(256) void k_p2(const float* __restrict__ x, const uint2* __restrict__ sel1,
                                            unsigned* __restrict__ h){
  __shared__ unsigned sh[4096];
  const int img  = blockIdx.x >> 3;
  const int part = blockIdx.x & 7;
  const unsigned b1 = sel1[img].x;
  const float4* p = (const float4*)(x + (size_t)img * HW + (size_t)part * 32768);
  for(int i = threadIdx.x; i < 4096; i += 256) sh[i] = 0;
  __syncthreads();
  for(int i = threadIdx.x; i < 8192; i += 256){
    float4 v = p[i];
    unsigned u;
    u = fmap_u(v.x); if((u >> 20) == b1) atomicAdd(&sh[(u >> 8) & 0xFFFu], 1u);
    u = fmap_u(v.y); if((u >> 20) == b1) atomicAdd(&sh[(u >> 8) & 0xFFFu], 1u);
    u = fmap_u(v.z); if((u >> 20) == b1) atomicAdd(&sh[(u >> 8) & 0xFFFu], 1u);
    u = fmap_u(v.w); if((u >> 20) == b1) atomicAdd(&sh[(u >> 8) & 0xFFFu], 1u);
  }
  __syncthreads();
  unsigned* hh = h + (size_t)img * 4096;
  for(int i = threadIdx.x; i < 4096; i += 256){
    unsigned c = sh[i];
    if(c) atomicAdd(&hh[i], c);
  }
}

// pass 3: among elements whose top-24 matches (sel1,sel2), histogram low 8 bits
__global__ __launch_bounds__(256) void k_p3(const float* __restrict__ x, const uint2* __restrict__ sel1,
                                            const uint2* __restrict__ sel2, unsigned* __restrict__ h){
  __shared__ unsigned sh[256];
  const int img  = blockIdx.x >> 3;
  const int part = blockIdx.x & 7;
  const unsigned key = (sel1[img].x << 12) | sel2[img].x;   // top 24 bits
  const float4* p = (const float4*)(x + (size_t)img * HW + (size_t)part * 32768);
  if(threadIdx.x < 256) sh[threadIdx.x] = 0;
  __syncthreads();
  for(int i = threadIdx.x; i < 8192; i += 256){
    float4 v = p[i];
    unsigned u;
    u = fmap_u(v.x); if((u >> 8) == key) atomicAdd(&sh[u & 0xFFu], 1u);
    u = fmap_u(v.y); if((u >> 8) == key) atomicAdd(&sh[u & 0xFFu], 1u);
    u = fmap_u(v.z); if((u >> 8) == key) atomicAdd(&sh[u & 0xFFu], 1u);
    u = fmap_u(v.w); if((u >> 8) == key) atomicAdd(&sh[u & 0xFFu], 1u);
  }
  __syncthreads();
  unsigned* hh = h + (size_t)img * 256;
  if(threadIdx.x < 256){
    unsigned c = sh[threadIdx.x];
    if(c) atomicAdd(&hh[threadIdx.x], c);
  }
}

// scan over 4096 bins: find bin containing rank; output (bin, residual rank)
__global__ void k_scan4096(const unsigned* __restrict__ h, const uint2* __restrict__ rsel,
                           uint2* __restrict__ osel, unsigned fixedRank, int useFixed){
  int img = blockIdx.x, t = threadIdx.x;
  const unsigned* hh = h + (size_t)img * 4096;
  __shared__ unsigned csum[256];
  unsigned s = 0;
  for(int j = 0; j < 16; j++) s += hh[t * 16 + j];
  csum[t] = s; __syncthreads();
  if(t == 0){
    unsigned k = useFixed ? fixedRank : rsel[img].y;
    unsigned cum = 0; int chunk = 0;
    for(; chunk < 256; ++chunk){ if(cum + csum[chunk] > k) break; cum += csum[chunk]; }
    int b = chunk * 16;
    for(;; ++b){ unsigned c = hh[b]; if(cum + c > k) break; cum += c; }
    osel[img] = make_uint2((unsigned)b, k - cum);
  }
}

// final 256-bin scan -> median value
__global__ void k_s256(const unsigned* __restrict__ h, const uint2* __restrict__ sel1,
                       const uint2* __restrict__ sel2, float* __restrict__ med){
  int img = blockIdx.x;
  if(threadIdx.x == 0){
    const unsigned* hh = h + (size_t)img * 256;
    unsigned k = sel2[img].y, cum = 0; int b = 0;
    for(;; ++b){ unsigned c = hh[b]; if(cum + c > k) break; cum += c; }
    unsigned u = (sel1[img].x << 20) | (sel2[img].x << 8) | (unsigned)b;
    med[img] = funmap_u(u) + 0.2f;
  }
}

// ---- row pass: t1[r][n] = sum_k padded[r][k] * Dir[(n-k)&511] ----
__global__ __launch_bounds__(256) void k_rowpass(
    const float* __restrict__ x, const float* __restrict__ mask,
    const float* __restrict__ med, const float* __restrict__ Dir,
    float* __restrict__ t1)
{
  __shared__ alignas(16) float As[BK][BM];
  __shared__ alignas(16) float Bs[BK][BN];
  __shared__ float DirS[512];
  const int t  = threadIdx.x;
  const int n0 = blockIdx.x * BN;
  const int r0 = blockIdx.y * BM;
  const int bc = r0 >> 9;
  const int bb = bc / 3;
  const int h0 = r0 & 511;
  const float mv = med[bc];

  for(int i = t; i < 512; i += 256) DirS[i] = Dir[i];

  const int lr = t >> 2;
  const int lk = (t & 3) << 2;
  const int bn = (t & 31) << 2;
  const int bk = t >> 5;
  const int tx = t & 15, ty = t >> 4;

  float acc[8][8];
  #pragma unroll
  for(int i = 0; i < 8; i++)
    #pragma unroll
    for(int j = 0; j < 8; j++) acc[i][j] = 0.f;

  __syncthreads();

  for(int k0 = 0; k0 < 512; k0 += BK){
    #pragma unroll
    for(int p = 0; p < 2; p++){
      int row = lr + p * 64;
      const float4 xv = *(const float4*)(x    + (size_t)(r0 + row) * 512 + k0 + lk);
      const float4 mk = *(const float4*)(mask + (size_t)bb * HW + (size_t)(h0 + row) * 512 + k0 + lk);
      As[lk + 0][row] = (mk.x != 0.f) ? xv.x : mv;
      As[lk + 1][row] = (mk.y != 0.f) ? xv.y : mv;
      As[lk + 2][row] = (mk.z != 0.f) ? xv.z : mv;
      As[lk + 3][row] = (mk.w != 0.f) ? xv.w : mv;
    }
    #pragma unroll
    for(int p = 0; p < 2; p++){
      int kk = bk + p * 8;
      #pragma unroll
      for(int j = 0; j < 4; j++)
        Bs[kk][bn + j] = DirS[(n0 + bn + j - k0 - kk) & 511];
    }
    __syncthreads();
    #pragma unroll
    for(int k = 0; k < BK; k++){
      float4 a0 = *(const float4*)&As[k][ty * 8];
      float4 a1 = *(const float4*)&As[k][ty * 8 + 4];
      float4 b0 = *(const float4*)&Bs[k][tx * 8];
      float4 b1 = *(const float4*)&Bs[k][tx * 8 + 4];
      float av[8] = {a0.x,a0.y,a0.z,a0.w,a1.x,a1.y,a1.z,a1.w};
      float bv[8] = {b0.x,b0.y,b0.z,b0.w,b1.x,b1.y,b1.z,b1.w};
      #pragma unroll
      for(int i = 0; i < 8; i++)
        #pragma unroll
        for(int j = 0; j < 8; j++)
          acc[i][j] = fmaf(av[i], bv[j], acc[i][j]);
    }
    __syncthreads();
  }
  #pragma unroll
  for(int i = 0; i < 8; i++){
    float* dst = t1 + (size_t)(r0 + ty * 8 + i) * 512 + n0 + tx * 8;
    *(float4*)dst       = make_float4(acc[i][0], acc[i][1], acc[i][2], acc[i][3]);
    *(float4*)(dst + 4) = make_float4(acc[i][4], acc[i][5], acc[i][6], acc[i][7]);
  }
}

// ---- col pass: res[h'][w] = | sum_h Dir[(h-h')&511] * t1[h][w] | ----
__global__ __launch_bounds__(256) void k_colpass(
    const float* __restrict__ t1, const float* __restrict__ Dir,
    float* __restrict__ res)
{
  __shared__ alignas(16) float As[BK][BM];
  __shared__ alignas(16) float Bs[BK][BN];
  __shared__ float DirS[512];
  const int t   = threadIdx.x;
  const int w0  = blockIdx.x * BN;
  const int hp0 = blockIdx.y * BM;
  const int img = blockIdx.z;
  const float* timg = t1 + (size_t)img * HW;

  for(int i = t; i < 512; i += 256) DirS[i] = Dir[i];

  const int lr = t >> 2;
  const int lk = (t & 3) << 2;
  const int bn = (t & 31) << 2;
  const int bk = t >> 5;
  const int tx = t & 15, ty = t >> 4;

  float acc[8][8];
  #pragma unroll
  for(int i = 0; i < 8; i++)
    #pragma unroll
    for(int j = 0; j < 8; j++) acc[i][j] = 0.f;

  __syncthreads();

  for(int k0 = 0; k0 < 512; k0 += BK){
    #pragma unroll
    for(int p = 0; p < 2; p++){
      int row = lr + p * 64;
      #pragma unroll
      for(int j = 0; j < 4; j++)
        As[lk + j][row] = DirS[(k0 + lk + j - hp0 - row) & 511];
    }
    #pragma unroll
    for(int p = 0; p < 2; p++){
      int kk = bk + p * 8;
      *(float4*)&Bs[kk][bn] = *(const float4*)(timg + (size_t)(k0 + kk) * 512 + w0 + bn);
    }
    __syncthreads();
    #pragma unroll
    for(int k = 0; k < BK; k++){
      float4 a0 = *(const float4*)&As[k][ty * 8];
      float4 a1 = *(const float4*)&As[k][ty * 8 + 4];
      float4 b0 = *(const float4*)&Bs[k][tx * 8];
      float4 b1 = *(const float4*)&Bs[k][tx * 8 + 4];
      float av[8] = {a0.x,a0.y,a0.z,a0.w,a1.x,a1.y,a1.z,a1.w};
      float bv[8] = {b0.x,b0.y,b0.z,b0.w,b1.x,b1.y,b1.z,b1.w};
      #pragma unroll
      for(int i = 0; i < 8; i++)
        #pragma unroll
        for(int j = 0; j < 8; j++)
          acc[i][j] = fmaf(av[i], bv[j], acc[i][j]);
    }
    __syncthreads();
  }
  #pragma unroll
  for(int i = 0; i < 8; i++){
    float* dst = res + (size_t)img * HW + (size_t)(hp0 + ty * 8 + i) * 512 + w0 + tx * 8;
    *(float4*)dst       = make_float4(fabsf(acc[i][0]), fabsf(acc[i][1]), fabsf(acc[i][2]), fabsf(acc[i][3]));
    *(float4*)(dst + 4) = make_float4(fabsf(acc[i][4]), fabsf(acc[i][5]), fabsf(acc[i][6]), fabsf(acc[i][7]));
  }
}

// ---- histogram of q = trunc(res*256) (exact order statistics of quantized values) ----
__global__ __launch_bounds__(256) void k_qhist(const float* __restrict__ res, unsigned* __restrict__ qh){
  __shared__ unsigned sh[NQBIN];
  const int img  = blockIdx.x >> 3;
  const int part = blockIdx.x & 7;
  const float4* p = (const float4*)(res + (size_t)img * HW + (size_t)part * 32768);
  for(int i = threadIdx.x; i < NQBIN; i += 256) sh[i] = 0;
  __syncthreads();
  for(int i = threadIdx.x; i < 8192; i += 256){
    float4 v = p[i];
    int b0 = min((int)(v.x * 256.f), NQBIN - 1);
    int b1 = min((int)(v.y * 256.f), NQBIN - 1);
    int b2 = min((int)(v.z * 256.f), NQBIN - 1);
    int b3 = min((int)(v.w * 256.f), NQBIN - 1);
    atomicAdd(&sh[b0], 1u); atomicAdd(&sh[b1], 1u);
    atomicAdd(&sh[b2], 1u); atomicAdd(&sh[b3], 1u);
  }
  __syncthreads();
  unsigned* h = qh + (size_t)img * NQBIN;
  for(int i = threadIdx.x; i < NQBIN; i += 256){
    unsigned c = sh[i];
    if(c) atomicAdd(&h[i], c);
  }
}

// ---- percentiles (linear interp at 3% / 97%) -> (lo, 1/(hi-lo)) ----
__global__ void k_pct(const unsigned* __restrict__ qh, float2* __restrict__ prm){
  int img = blockIdx.x, t = threadIdx.x;
  const unsigned* h = qh + (size_t)img * NQBIN;
  __shared__ unsigned sh[NQBIN];
  for(int i = t; i < NQBIN; i += 256) sh[i] = h[i];
  __syncthreads();
  if(t == 0){
    const unsigned targ[4] = {7864u, 7865u, 254278u, 254279u};
    float v[4]; unsigned cum = 0; int b = 0;
    for(int q = 0; q < 4; q++){
      while(cum + sh[b] <= targ[q]){ cum += sh[b]; ++b; }
      v[q] = (float)b * (1.0f / 256.0f);
    }
    double plo = 0.03 * 262143.0;   // 7864.29
    double phi = 0.97 * 262143.0;   // 254278.71
    float lo = v[0] + (float)(plo - 7864.0)   * (v[1] - v[0]);
    float hi = v[2] + (float)(phi - 254278.0) * (v[3] - v[2]);
    prm[img] = make_float2(lo, 1.0f / (hi - lo));
  }
}

// ---- in-place normalize: out = (res - lo) * inv * mask ----
__global__ __launch_bounds__(256) void k_norm(float* __restrict__ out, const float* __restrict__ mask,
                                              const float2* __restrict__ prm){
  size_t i4 = (size_t)blockIdx.x * blockDim.x + threadIdx.x;
  const size_t total4 = (size_t)NIMG * HW / 4;
  const size_t step = (size_t)gridDim.x * blockDim.x;
  for(; i4 < total4; i4 += step){
    size_t i = i4 * 4;
    int bc = (int)(i >> 18);
    int bb = bc / 3;
    size_t mi = ((size_t)bb << 18) + (i & 0x3FFFFu);
    float4 r = *(float4*)(out + i);
    float4 m = *(const float4*)(mask + mi);
    float2 p = prm[bc];
    float4 o;
    o.x = (r.x - p.x) * p.y * m.x;
    o.y = (r.y - p.x) * p.y * m.y;
    o.z = (r.z - p.x) * p.y * m.z;
    o.w = (r.w - p.x) * p.y * m.w;
    *(float4*)(out + i) = o;
  }
}

extern "C" void kernel_launch(void* const* d_in, const int* in_sizes, int n_in,
                              void* d_out, int out_size, void* d_ws, size_t ws_size,
                              hipStream_t stream)
{
  const float* x       = (const float*)d_in[0];
  const float* mask    = (const float*)d_in[1];
  const float* fmap_in = (const float*)d_in[2];
  float* out = (float*)d_out;

  const size_t T1_BYTES = (size_t)NIMG * HW * 4;   // 100663296
  char* ws = (char*)d_ws;
  float* t1 = (float*)ws;                          // lives rowpass..colpass
  // radix-select histograms alias the (not-yet-written) t1 region:
  unsigned* h1 = (unsigned*)ws;                    // 96*4096*4 = 1.5 MB
  unsigned* h2 = (unsigned*)(ws + (size_t)NIMG * 4096 * 4);           // 1.5 MB
  unsigned* h3 = (unsigned*)(ws + (size_t)NIMG * 4096 * 8);           // 96 KB
  unsigned* qhist = (unsigned*)ws;                 // alias: used after t1 dead (1.5 MB)
  char* tail = ws + T1_BYTES;
  float*  Dir  = (float*)tail;                     // 2048 B
  float*  med  = (float*)(tail + 2048);            // 384 B (padded to 512)
  uint2*  sel1 = (uint2*)(tail + 2560);            // 768 B
  uint2*  sel2 = (uint2*)(tail + 3328);            // 768 B
  float2* prm  = (float2*)(tail + 4096);           // 768 B

  k_dir<<<512, 256, 0, stream>>>(fmap_in, Dir);

  // 3-pass LDS radix select for exact median (rank 131071 of 262144)
  hipMemsetAsync(h1, 0, (size_t)NIMG * (4096 + 4096 + 256) * 4, stream);
  k_p1<<<NIMG * 8, 256, 0, stream>>>(x, h1);
  k_scan4096<<<NIMG, 256, 0, stream>>>(h1, nullptr, sel1, 131071u, 1);
  k_p2<<<NIMG * 8, 256, 0, stream>>>(x, sel1, h2);
  k_scan4096<<<NIMG, 256, 0, stream>>>(h2, sel1, sel2, 0u, 0);
  k_p3<<<NIMG * 8, 256, 0, stream>>>(x, sel1, sel2, h3);
  k_s256<<<NIMG, 256, 0, stream>>>(h3, sel1, sel2, med);

  k_rowpass<<<dim3(512 / BN, (NIMG * 512) / BM), 256, 0, stream>>>(x, mask, med, Dir, t1);
  k_colpass<<<dim3(512 / BN, 512 / BM, NIMG), 256, 0, stream>>>(t1, Dir, out);

  hipMemsetAsync(qhist, 0, (size_t)NIMG * NQBIN * 4, stream);
  k_qhist<<<NIMG * 8, 256, 0, stream>>>(out, qhist);
  k_pct<<<NIMG, 256, 0, stream>>>(qhist, prm);
  k_norm<<<2048, 256, 0, stream>>>(out, mask, prm);
}

// Round 4
// 345.152 us; speedup vs baseline: 4.2379x; 2.2662x over previous
//
#include <hip/hip_runtime.h>
#include <math.h>

#define HW 262144     // 512*512
#define NIMG 96       // B*C
#define NQBIN 4096

typedef __attribute__((ext_vector_type(8))) short bf16x8;
typedef __attribute__((ext_vector_type(4))) float f32x4;

// ---- helpers ----
__device__ __forceinline__ unsigned fmap_u(float f){
  unsigned u = __float_as_uint(f);
  return (u & 0x80000000u) ? ~u : (u | 0x80000000u);
}
__device__ __forceinline__ float funmap_u(unsigned u){
  unsigned v = (u & 0x80000000u) ? (u & 0x7fffffffu) : ~u;
  return __uint_as_float(v);
}
__device__ __forceinline__ unsigned bf16rne(float f){
  unsigned u = __float_as_uint(f);
  return (u + 0x7fffu + ((u >> 16) & 1u)) >> 16;
}
__device__ __forceinline__ void split2(float v, unsigned &h, unsigned &l){
  h = bf16rne(v);
  float fh = __uint_as_float(h << 16);
  l = bf16rne(v - fh);
}

// ---- Dir[n] = Re( ifft(filter_map row 0) )[n], computed in double ----
__global__ void k_dir(const float* __restrict__ fmap_in, float* __restrict__ Dir){
  int n = blockIdx.x;
  int t = threadIdx.x;
  double s = 0.0;
  for(int c = t; c < 512; c += 256){
    int a = (c * n) & 511;
    s += (double)fmap_in[c] * cos(6.283185307179586476925287 * (double)a / 512.0);
  }
  __shared__ double red[256];
  red[t] = s; __syncthreads();
  for(int off = 128; off; off >>= 1){
    if(t < off) red[t] += red[t + off];
    __syncthreads();
  }
  if(t == 0) Dir[n] = (float)(red[0] / 512.0);
}

// ---- Cm[a][b] = Dir[(a-b)&511], split bf16 hi/lo (1 MB, L2-resident) ----
__global__ void k_cmat(const float* __restrict__ Dir, unsigned short* __restrict__ CmH,
                       unsigned short* __restrict__ CmL){
  int a = blockIdx.x;
  for(int b = threadIdx.x; b < 512; b += 256){
    float d = Dir[(a - b) & 511];
    unsigned h, l; split2(d, h, l);
    CmH[(size_t)a * 512 + b] = (unsigned short)h;
    CmL[(size_t)a * 512 + b] = (unsigned short)l;
  }
}

// ==== exact median via 3-pass LDS radix select (12 / 12 / 8 bits) ====
__global__ __launch_bounds__(256) void k_p1(const float* __restrict__ x, unsigned* __restrict__ h){
  __shared__ unsigned sh[4096];
  const int img  = blockIdx.x >> 3;
  const int part = blockIdx.x & 7;
  const float4* p = (const float4*)(x + (size_t)img * HW + (size_t)part * 32768);
  for(int i = threadIdx.x; i < 4096; i += 256) sh[i] = 0;
  __syncthreads();
  for(int i = threadIdx.x; i < 8192; i += 256){
    float4 v = p[i];
    atomicAdd(&sh[fmap_u(v.x) >> 20], 1u);
    atomicAdd(&sh[fmap_u(v.y) >> 20], 1u);
    atomicAdd(&sh[fmap_u(v.z) >> 20], 1u);
    atomicAdd(&sh[fmap_u(v.w) >> 20], 1u);
  }
  __syncthreads();
  unsigned* hh = h + (size_t)img * 4096;
  for(int i = threadIdx.x; i < 4096; i += 256){
    unsigned c = sh[i];
    if(c) atomicAdd(&hh[i], c);
  }
}

__global__ __launch_bounds__(256) void k_p2(const float* __restrict__ x, const uint2* __restrict__ sel1,
                                            unsigned* __restrict__ h){
  __shared__ unsigned sh[4096];
  const int img  = blockIdx.x >> 3;
  const int part = blockIdx.x & 7;
  const unsigned b1 = sel1[img].x;
  const float4* p = (const float4*)(x + (size_t)img * HW + (size_t)part * 32768);
  for(int i = threadIdx.x; i < 4096; i += 256) sh[i] = 0;
  __syncthreads();
  for(int i = threadIdx.x; i < 8192; i += 256){
    float4 v = p[i];
    unsigned u;
    u = fmap_u(v.x); if((u >> 20) == b1) atomicAdd(&sh[(u >> 8) & 0xFFFu], 1u);
    u = fmap_u(v.y); if((u >> 20) == b1) atomicAdd(&sh[(u >> 8) & 0xFFFu], 1u);
    u = fmap_u(v.z); if((u >> 20) == b1) atomicAdd(&sh[(u >> 8) & 0xFFFu], 1u);
    u = fmap_u(v.w); if((u >> 20) == b1) atomicAdd(&sh[(u >> 8) & 0xFFFu], 1u);
  }
  __syncthreads();
  unsigned* hh = h + (size_t)img * 4096;
  for(int i = threadIdx.x; i < 4096; i += 256){
    unsigned c = sh[i];
    if(c) atomicAdd(&hh[i], c);
  }
}

__global__ __launch_bounds__(256) void k_p3(const float* __restrict__ x, const uint2* __restrict__ sel1,
                                            const uint2* __restrict__ sel2, unsigned* __restrict__ h){
  __shared__ unsigned sh[256];
  const int img  = blockIdx.x >> 3;
  const int part = blockIdx.x & 7;
  const unsigned key = (sel1[img].x << 12) | sel2[img].x;
  const float4* p = (const float4*)(x + (size_t)img * HW + (size_t)part * 32768);
  if(threadIdx.x < 256) sh[threadIdx.x] = 0;
  __syncthreads();
  for(int i = threadIdx.x; i < 8192; i += 256){
    float4 v = p[i];
    unsigned u;
    u = fmap_u(v.x); if((u >> 8) == key) atomicAdd(&sh[u & 0xFFu], 1u);
    u = fmap_u(v.y); if((u >> 8) == key) atomicAdd(&sh[u & 0xFFu], 1u);
    u = fmap_u(v.z); if((u >> 8) == key) atomicAdd(&sh[u & 0xFFu], 1u);
    u = fmap_u(v.w); if((u >> 8) == key) atomicAdd(&sh[u & 0xFFu], 1u);
  }
  __syncthreads();
  unsigned* hh = h + (size_t)img * 256;
  if(threadIdx.x < 256){
    unsigned c = sh[threadIdx.x];
    if(c) atomicAdd(&hh[threadIdx.x], c);
  }
}

__global__ void k_scan4096(const unsigned* __restrict__ h, const uint2* __restrict__ rsel,
                           uint2* __restrict__ osel, unsigned fixedRank, int useFixed){
  int img = blockIdx.x, t = threadIdx.x;
  const unsigned* hh = h + (size_t)img * 4096;
  __shared__ unsigned csum[256];
  unsigned s = 0;
  for(int j = 0; j < 16; j++) s += hh[t * 16 + j];
  csum[t] = s; __syncthreads();
  if(t == 0){
    unsigned k = useFixed ? fixedRank : rsel[img].y;
    unsigned cum = 0; int chunk = 0;
    for(; chunk < 256; ++chunk){ if(cum + csum[chunk] > k) break; cum += csum[chunk]; }
    int b = chunk * 16;
    for(;; ++b){ unsigned c = hh[b]; if(cum + c > k) break; cum += c; }
    osel[img] = make_uint2((unsigned)b, k - cum);
  }
}

__global__ void k_s256(const unsigned* __restrict__ h, const uint2* __restrict__ sel1,
                       const uint2* __restrict__ sel2, float* __restrict__ med){
  int img = blockIdx.x;
  if(threadIdx.x == 0){
    const unsigned* hh = h + (size_t)img * 256;
    unsigned k = sel2[img].y, cum = 0; int b = 0;
    for(;; ++b){ unsigned c = hh[b]; if(cum + c > k) break; cum += c; }
    unsigned u = (sel1[img].x << 20) | (sel2[img].x << 8) | (unsigned)b;
    med[img] = funmap_u(u) + 0.2f;
  }
}

// ==== MFMA row pass: t1T[img][n][h] = bf16( sum_k padded[r][k] * Cm[n][k] ) ====
__global__ __launch_bounds__(256, 2) void k_rowpass(
    const float* __restrict__ x, const float* __restrict__ mask,
    const float* __restrict__ med,
    const unsigned short* __restrict__ CmH, const unsigned short* __restrict__ CmL,
    unsigned short* __restrict__ t1h)
{
  __shared__ __align__(16) unsigned short AsH[128][40];
  __shared__ __align__(16) unsigned short AsL[128][40];
  __shared__ __align__(16) unsigned short BsH[128][40];
  __shared__ __align__(16) unsigned short BsL[128][40];

  // XCD swizzle: 4 sibling n-blocks (same rows) on the same XCD
  const int b    = blockIdx.x;           // 0..1535
  const int xcd  = b & 7;
  const int i8   = b >> 3;               // 0..191
  const int rblk = xcd * 48 + (i8 >> 2); // 0..383
  const int nblk = i8 & 3;
  const int r0 = rblk * 128;
  const int n0 = nblk * 128;
  const int bc = r0 >> 9;
  const int bb = bc / 3;
  const float mv = med[bc];

  const int t    = threadIdx.x;
  const int lane = t & 63;
  const int wv   = t >> 6;
  const int wm   = (wv >> 1) * 64;
  const int wn   = (wv & 1) * 64;
  const int fr   = lane & 15;
  const int fg   = lane >> 4;

  f32x4 acc[4][4];
  #pragma unroll
  for(int i = 0; i < 4; i++)
    #pragma unroll
    for(int j = 0; j < 4; j++) acc[i][j] = (f32x4){0.f, 0.f, 0.f, 0.f};

  const int sm = t >> 1;             // staging row 0..127
  const int kc = (t & 1) << 4;       // 0 or 16

  for(int k0 = 0; k0 < 512; k0 += 32){
    // --- stage A: median-padded x, split to bf16 hi/lo (16 ushorts/thread) ---
    {
      const float* xr = x    + ((size_t)(r0 + sm) << 9) + k0 + kc;
      const float* mr = mask + (size_t)bb * HW + ((size_t)((r0 + sm) & 511) << 9) + k0 + kc;
      #pragma unroll
      for(int q = 0; q < 4; q++){
        float4 xv = *(const float4*)(xr + q * 4);
        float4 mk = *(const float4*)(mr + q * 4);
        float v0 = (mk.x != 0.f) ? xv.x : mv;
        float v1 = (mk.y != 0.f) ? xv.y : mv;
        float v2 = (mk.z != 0.f) ? xv.z : mv;
        float v3 = (mk.w != 0.f) ? xv.w : mv;
        unsigned h0,h1,h2,h3,l0,l1,l2,l3;
        split2(v0,h0,l0); split2(v1,h1,l1); split2(v2,h2,l2); split2(v3,h3,l3);
        *(uint2*)&AsH[sm][kc + q*4] = make_uint2((h1<<16)|h0, (h3<<16)|h2);
        *(uint2*)&AsL[sm][kc + q*4] = make_uint2((l1<<16)|l0, (l3<<16)|l2);
      }
    }
    // --- stage B: circulant tile (16 ushorts/thread = 2x uint4) ---
    {
      const size_t gofs = ((size_t)(n0 + sm) << 9) + k0 + kc;
      *(uint4*)&BsH[sm][kc]     = *(const uint4*)(CmH + gofs);
      *(uint4*)&BsH[sm][kc + 8] = *(const uint4*)(CmH + gofs + 8);
      *(uint4*)&BsL[sm][kc]     = *(const uint4*)(CmL + gofs);
      *(uint4*)&BsL[sm][kc + 8] = *(const uint4*)(CmL + gofs + 8);
    }
    __syncthreads();

    bf16x8 ah[4], al[4], bh[4], bl[4];
    #pragma unroll
    for(int i = 0; i < 4; i++){
      ah[i] = *(const bf16x8*)&AsH[wm + i*16 + fr][fg*8];
      al[i] = *(const bf16x8*)&AsL[wm + i*16 + fr][fg*8];
    }
    #pragma unroll
    for(int j = 0; j < 4; j++){
      bh[j] = *(const bf16x8*)&BsH[wn + j*16 + fr][fg*8];
      bl[j] = *(const bf16x8*)&BsL[wn + j*16 + fr][fg*8];
    }
    #pragma unroll
    for(int i = 0; i < 4; i++)
      #pragma unroll
      for(int j = 0; j < 4; j++){
        acc[i][j] = __builtin_amdgcn_mfma_f32_16x16x32_bf16(ah[i], bh[j], acc[i][j], 0, 0, 0);
        acc[i][j] = __builtin_amdgcn_mfma_f32_16x16x32_bf16(ah[i], bl[j], acc[i][j], 0, 0, 0);
        acc[i][j] = __builtin_amdgcn_mfma_f32_16x16x32_bf16(al[i], bh[j], acc[i][j], 0, 0, 0);
      }
    __syncthreads();
  }

  // --- store t1 transposed as single bf16: t1T[img][n][h] ---
  const int img = r0 >> 9;
  const int hb  = r0 & 511;
  #pragma unroll
  for(int i = 0; i < 4; i++)
    #pragma unroll
    for(int j = 0; j < 4; j++){
      f32x4 a = acc[i][j];
      unsigned b0 = bf16rne(a[0]), b1 = bf16rne(a[1]), b2 = bf16rne(a[2]), b3 = bf16rne(a[3]);
      int n = n0 + wn + j*16 + fr;
      int h = hb + wm + i*16 + fg*4;
      *(uint2*)&t1h[(size_t)img * HW + ((size_t)n << 9) + h] =
          make_uint2((b1<<16)|b0, (b3<<16)|b2);
    }
}

// ==== MFMA col pass: res[img][h'][w] = | sum_h Cm[h'][h] * t1T[img][w][h] | ====
__global__ __launch_bounds__(256, 2) void k_colpass(
    const unsigned short* __restrict__ t1h,
    const unsigned short* __restrict__ CmH, const unsigned short* __restrict__ CmL,
    float* __restrict__ res)
{
  __shared__ __align__(16) unsigned short AsH[128][40];
  __shared__ __align__(16) unsigned short AsL[128][40];
  __shared__ __align__(16) unsigned short Bs [128][40];

  // XCD swizzle: all 16 blocks of one image on the same XCD (t1 image L2-resident)
  const int b    = blockIdx.x;           // 0..1535
  const int xcd  = b & 7;
  const int i8   = b >> 3;               // 0..191
  const int img  = xcd * 12 + (i8 >> 4);
  const int r16  = i8 & 15;
  const int hp0  = (r16 >> 2) * 128;
  const int w0   = (r16 & 3) * 128;

  const int t    = threadIdx.x;
  const int lane = t & 63;
  const int wv   = t >> 6;
  const int wm   = (wv >> 1) * 64;
  const int wn   = (wv & 1) * 64;
  const int fr   = lane & 15;
  const int fg   = lane >> 4;

  f32x4 acc[4][4];
  #pragma unroll
  for(int i = 0; i < 4; i++)
    #pragma unroll
    for(int j = 0; j < 4; j++) acc[i][j] = (f32x4){0.f, 0.f, 0.f, 0.f};

  const int sm = t >> 1;
  const int kc = (t & 1) << 4;

  for(int k0 = 0; k0 < 512; k0 += 32){
    // --- stage A: circulant tile rows hp0+m (16 ushorts/thread) ---
    {
      const size_t gofs = ((size_t)(hp0 + sm) << 9) + k0 + kc;
      *(uint4*)&AsH[sm][kc]     = *(const uint4*)(CmH + gofs);
      *(uint4*)&AsH[sm][kc + 8] = *(const uint4*)(CmH + gofs + 8);
      *(uint4*)&AsL[sm][kc]     = *(const uint4*)(CmL + gofs);
      *(uint4*)&AsL[sm][kc + 8] = *(const uint4*)(CmL + gofs + 8);
    }
    // --- stage B: t1T tile, contiguous along h (16 ushorts/thread) ---
    {
      const size_t gofs = (size_t)img * HW + ((size_t)(w0 + sm) << 9) + k0 + kc;
      *(uint4*)&Bs[sm][kc]     = *(const uint4*)(t1h + gofs);
      *(uint4*)&Bs[sm][kc + 8] = *(const uint4*)(t1h + gofs + 8);
    }
    __syncthreads();

    bf16x8 ah[4], al[4], bv[4];
    #pragma unroll
    for(int i = 0; i < 4; i++){
      ah[i] = *(const bf16x8*)&AsH[wm + i*16 + fr][fg*8];
      al[i] = *(const bf16x8*)&AsL[wm + i*16 + fr][fg*8];
    }
    #pragma unroll
    for(int j = 0; j < 4; j++)
      bv[j] = *(const bf16x8*)&Bs[wn + j*16 + fr][fg*8];

    #pragma unroll
    for(int i = 0; i < 4; i++)
      #pragma unroll
      for(int j = 0; j < 4; j++){
        acc[i][j] = __builtin_amdgcn_mfma_f32_16x16x32_bf16(ah[i], bv[j], acc[i][j], 0, 0, 0);
        acc[i][j] = __builtin_amdgcn_mfma_f32_16x16x32_bf16(al[i], bv[j], acc[i][j], 0, 0, 0);
      }
    __syncthreads();
  }

  float* rimg = res + (size_t)img * HW;
  #pragma unroll
  for(int i = 0; i < 4; i++)
    #pragma unroll
    for(int j = 0; j < 4; j++){
      f32x4 a = acc[i][j];
      int w  = w0 + wn + j*16 + fr;
      int hp = hp0 + wm + i*16 + fg*4;
      #pragma unroll
      for(int r = 0; r < 4; r++)
        rimg[((size_t)(hp + r) << 9) + w] = fabsf(a[r]);
    }
}

// ---- histogram of q = trunc(res*256) ----
__global__ __launch_bounds__(256) void k_qhist(const float* __restrict__ res, unsigned* __restrict__ qh){
  __shared__ unsigned sh[NQBIN];
  const int img  = blockIdx.x >> 3;
  const int part = blockIdx.x & 7;
  const float4* p = (const float4*)(res + (size_t)img * HW + (size_t)part * 32768);
  for(int i = threadIdx.x; i < NQBIN; i += 256) sh[i] = 0;
  __syncthreads();
  for(int i = threadIdx.x; i < 8192; i += 256){
    float4 v = p[i];
    int b0 = min((int)(v.x * 256.f), NQBIN - 1);
    int b1 = min((int)(v.y * 256.f), NQBIN - 1);
    int b2 = min((int)(v.z * 256.f), NQBIN - 1);
    int b3 = min((int)(v.w * 256.f), NQBIN - 1);
    atomicAdd(&sh[b0], 1u); atomicAdd(&sh[b1], 1u);
    atomicAdd(&sh[b2], 1u); atomicAdd(&sh[b3], 1u);
  }
  __syncthreads();
  unsigned* h = qh + (size_t)img * NQBIN;
  for(int i = threadIdx.x; i < NQBIN; i += 256){
    unsigned c = sh[i];
    if(c) atomicAdd(&h[i], c);
  }
}

// ---- percentiles (linear interp at 3% / 97%) -> (lo, 1/(hi-lo)) ----
__global__ void k_pct(const unsigned* __restrict__ qh, float2* __restrict__ prm){
  int img = blockIdx.x, t = threadIdx.x;
  const unsigned* h = qh + (size_t)img * NQBIN;
  __shared__ unsigned sh[NQBIN];
  for(int i = t; i < NQBIN; i += 256) sh[i] = h[i];
  __syncthreads();
  if(t == 0){
    const unsigned targ[4] = {7864u, 7865u, 254278u, 254279u};
    float v[4]; unsigned cum = 0; int b = 0;
    for(int q = 0; q < 4; q++){
      while(cum + sh[b] <= targ[q]){ cum += sh[b]; ++b; }
      v[q] = (float)b * (1.0f / 256.0f);
    }
    double plo = 0.03 * 262143.0;
    double phi = 0.97 * 262143.0;
    float lo = v[0] + (float)(plo - 7864.0)   * (v[1] - v[0]);
    float hi = v[2] + (float)(phi - 254278.0) * (v[3] - v[2]);
    prm[img] = make_float2(lo, 1.0f / (hi - lo));
  }
}

// ---- in-place normalize: out = (res - lo) * inv * mask ----
__global__ __launch_bounds__(256) void k_norm(float* __restrict__ out, const float* __restrict__ mask,
                                              const float2* __restrict__ prm){
  size_t i4 = (size_t)blockIdx.x * blockDim.x + threadIdx.x;
  const size_t total4 = (size_t)NIMG * HW / 4;
  const size_t step = (size_t)gridDim.x * blockDim.x;
  for(; i4 < total4; i4 += step){
    size_t i = i4 * 4;
    int bc = (int)(i >> 18);
    int bb = bc / 3;
    size_t mi = ((size_t)bb << 18) + (i & 0x3FFFFu);
    float4 r = *(float4*)(out + i);
    float4 m = *(const float4*)(mask + mi);
    float2 p = prm[bc];
    float4 o;
    o.x = (r.x - p.x) * p.y * m.x;
    o.y = (r.y - p.x) * p.y * m.y;
    o.z = (r.z - p.x) * p.y * m.z;
    o.w = (r.w - p.x) * p.y * m.w;
    *(float4*)(out + i) = o;
  }
}

extern "C" void kernel_launch(void* const* d_in, const int* in_sizes, int n_in,
                              void* d_out, int out_size, void* d_ws, size_t ws_size,
                              hipStream_t stream)
{
  const float* x       = (const float*)d_in[0];
  const float* mask    = (const float*)d_in[1];
  const float* fmap_in = (const float*)d_in[2];
  float* out = (float*)d_out;

  const size_t T1_BYTES = (size_t)NIMG * HW * 2;   // 50,331,648 (bf16 t1T)
  char* ws = (char*)d_ws;
  unsigned short* t1h = (unsigned short*)ws;        // lives rowpass..colpass
  // radix histograms alias the (not-yet-written) t1 region:
  unsigned* h1 = (unsigned*)ws;                                        // 1.5 MB
  unsigned* h2 = (unsigned*)(ws + (size_t)NIMG * 4096 * 4);            // 1.5 MB
  unsigned* h3 = (unsigned*)(ws + (size_t)NIMG * 4096 * 8);            // 96 KB
  unsigned* qhist = (unsigned*)ws;                  // alias: used after t1 dead
  char* tail = ws + T1_BYTES;
  float*          Dir = (float*)tail;                                  // 2048 B
  unsigned short* CmH = (unsigned short*)(tail + 2048);                // 512 KB
  unsigned short* CmL = (unsigned short*)(tail + 2048 + 524288);       // 512 KB
  char* tail2 = tail + 2048 + 1048576;
  float*  med  = (float*)tail2;                     // 384 B (padded to 512)
  uint2*  sel1 = (uint2*)(tail2 + 512);
  uint2*  sel2 = (uint2*)(tail2 + 1280);
  float2* prm  = (float2*)(tail2 + 2048);

  k_dir<<<512, 256, 0, stream>>>(fmap_in, Dir);
  k_cmat<<<512, 256, 0, stream>>>(Dir, CmH, CmL);

  // 3-pass LDS radix select for exact median (rank 131071 of 262144)
  hipMemsetAsync(h1, 0, (size_t)NIMG * (4096 + 4096 + 256) * 4, stream);
  k_p1<<<NIMG * 8, 256, 0, stream>>>(x, h1);
  k_scan4096<<<NIMG, 256, 0, stream>>>(h1, nullptr, sel1, 131071u, 1);
  k_p2<<<NIMG * 8, 256, 0, stream>>>(x, sel1, h2);
  k_scan4096<<<NIMG, 256, 0, stream>>>(h2, sel1, sel2, 0u, 0);
  k_p3<<<NIMG * 8, 256, 0, stream>>>(x, sel1, sel2, h3);
  k_s256<<<NIMG, 256, 0, stream>>>(h3, sel1, sel2, med);

  k_rowpass<<<1536, 256, 0, stream>>>(x, mask, med, CmH, CmL, t1h);
  k_colpass<<<1536, 256, 0, stream>>>(t1h, CmH, CmL, out);

  hipMemsetAsync(qhist, 0, (size_t)NIMG * NQBIN * 4, stream);
  k_qhist<<<NIMG * 8, 256, 0, stream>>>(out, qhist);
  k_pct<<<NIMG, 256, 0, stream>>>(qhist, prm);
  k_norm<<<2048, 256, 0, stream>>>(out, mask, prm);
}

// Round 5
// 303.673 us; speedup vs baseline: 4.8167x; 1.1366x over previous
//
#include <hip/hip_runtime.h>
#include <math.h>

#define HW 262144     // 512*512
#define NIMG 96       // B*C
#define NQBIN 4096

typedef __attribute__((ext_vector_type(8))) short bf16x8;
typedef __attribute__((ext_vector_type(4))) float f32x4;

// ---- helpers ----
__device__ __forceinline__ unsigned fmap_u(float f){
  unsigned u = __float_as_uint(f);
  return (u & 0x80000000u) ? ~u : (u | 0x80000000u);
}
__device__ __forceinline__ float funmap_u(unsigned u){
  unsigned v = (u & 0x80000000u) ? (u & 0x7fffffffu) : ~u;
  return __uint_as_float(v);
}
__device__ __forceinline__ unsigned bf16rne(float f){
  unsigned u = __float_as_uint(f);
  return (u + 0x7fffu + ((u >> 16) & 1u)) >> 16;
}
__device__ __forceinline__ void split2(float v, unsigned &h, unsigned &l){
  h = bf16rne(v);
  float fh = __uint_as_float(h << 16);
  l = bf16rne(v - fh);
}

// ---- Dir[n] = Re( ifft(filter_map row 0) )[n], computed in double ----
__global__ void k_dir(const float* __restrict__ fmap_in, float* __restrict__ Dir){
  int n = blockIdx.x;
  int t = threadIdx.x;
  double s = 0.0;
  for(int c = t; c < 512; c += 256){
    int a = (c * n) & 511;
    s += (double)fmap_in[c] * cos(6.283185307179586476925287 * (double)a / 512.0);
  }
  __shared__ double red[256];
  red[t] = s; __syncthreads();
  for(int off = 128; off; off >>= 1){
    if(t < off) red[t] += red[t + off];
    __syncthreads();
  }
  if(t == 0) Dir[n] = (float)(red[0] / 512.0);
}

// ---- Cm[a][b] = Dir[(a-b)&511], split bf16 hi/lo (1 MB, L2-resident) ----
__global__ void k_cmat(const float* __restrict__ Dir, unsigned short* __restrict__ CmH,
                       unsigned short* __restrict__ CmL){
  int a = blockIdx.x;
  for(int b = threadIdx.x; b < 512; b += 256){
    float d = Dir[(a - b) & 511];
    unsigned h, l; split2(d, h, l);
    CmH[(size_t)a * 512 + b] = (unsigned short)h;
    CmL[(size_t)a * 512 + b] = (unsigned short)l;
  }
}

// ==== exact-to-24-bits median via 2-pass LDS radix select (12 / 12 bits) ====
__global__ __launch_bounds__(256) void k_p1(const float* __restrict__ x, unsigned* __restrict__ h){
  __shared__ unsigned sh[4096];
  const int img  = blockIdx.x >> 3;
  const int part = blockIdx.x & 7;
  const float4* p = (const float4*)(x + (size_t)img * HW + (size_t)part * 32768);
  for(int i = threadIdx.x; i < 4096; i += 256) sh[i] = 0;
  __syncthreads();
  for(int i = threadIdx.x; i < 8192; i += 256){
    float4 v = p[i];
    atomicAdd(&sh[fmap_u(v.x) >> 20], 1u);
    atomicAdd(&sh[fmap_u(v.y) >> 20], 1u);
    atomicAdd(&sh[fmap_u(v.z) >> 20], 1u);
    atomicAdd(&sh[fmap_u(v.w) >> 20], 1u);
  }
  __syncthreads();
  unsigned* hh = h + (size_t)img * 4096;
  for(int i = threadIdx.x; i < 4096; i += 256){
    unsigned c = sh[i];
    if(c) atomicAdd(&hh[i], c);
  }
}

__global__ __launch_bounds__(256) void k_p2(const float* __restrict__ x, const uint2* __restrict__ sel1,
                                            unsigned* __restrict__ h){
  __shared__ unsigned sh[4096];
  const int img  = blockIdx.x >> 3;
  const int part = blockIdx.x & 7;
  const unsigned b1 = sel1[img].x;
  const float4* p = (const float4*)(x + (size_t)img * HW + (size_t)part * 32768);
  for(int i = threadIdx.x; i < 4096; i += 256) sh[i] = 0;
  __syncthreads();
  for(int i = threadIdx.x; i < 8192; i += 256){
    float4 v = p[i];
    unsigned u;
    u = fmap_u(v.x); if((u >> 20) == b1) atomicAdd(&sh[(u >> 8) & 0xFFFu], 1u);
    u = fmap_u(v.y); if((u >> 20) == b1) atomicAdd(&sh[(u >> 8) & 0xFFFu], 1u);
    u = fmap_u(v.z); if((u >> 20) == b1) atomicAdd(&sh[(u >> 8) & 0xFFFu], 1u);
    u = fmap_u(v.w); if((u >> 20) == b1) atomicAdd(&sh[(u >> 8) & 0xFFFu], 1u);
  }
  __syncthreads();
  unsigned* hh = h + (size_t)img * 4096;
  for(int i = threadIdx.x; i < 4096; i += 256){
    unsigned c = sh[i];
    if(c) atomicAdd(&hh[i], c);
  }
}

// pass-1 scan: find 12-bit bin containing rank 131071; (bin, residual rank)
__global__ void k_scan1(const unsigned* __restrict__ h, uint2* __restrict__ osel){
  int img = blockIdx.x, t = threadIdx.x;
  const unsigned* hh = h + (size_t)img * 4096;
  __shared__ unsigned csum[256];
  unsigned s = 0;
  for(int j = 0; j < 16; j++) s += hh[t * 16 + j];
  csum[t] = s; __syncthreads();
  if(t == 0){
    unsigned k = 131071u, cum = 0; int chunk = 0;
    for(; chunk < 256; ++chunk){ if(cum + csum[chunk] > k) break; cum += csum[chunk]; }
    int b = chunk * 16;
    for(;; ++b){ unsigned c = hh[b]; if(cum + c > k) break; cum += c; }
    osel[img] = make_uint2((unsigned)b, k - cum);
  }
}

// pass-2 scan: 24-bit prefix known; emit median = prefix-bin midpoint (+0.2)
// error <= 128 fp32-ulp (~8e-6 abs) -- negligible vs bf16 path
__global__ void k_scan_med(const unsigned* __restrict__ h, const uint2* __restrict__ sel1,
                           float* __restrict__ med){
  int img = blockIdx.x, t = threadIdx.x;
  const unsigned* hh = h + (size_t)img * 4096;
  __shared__ unsigned csum[256];
  unsigned s = 0;
  for(int j = 0; j < 16; j++) s += hh[t * 16 + j];
  csum[t] = s; __syncthreads();
  if(t == 0){
    unsigned k = sel1[img].y, cum = 0; int chunk = 0;
    for(; chunk < 256; ++chunk){ if(cum + csum[chunk] > k) break; cum += csum[chunk]; }
    int b = chunk * 16;
    for(;; ++b){ unsigned c = hh[b]; if(cum + c > k) break; cum += c; }
    unsigned u = (sel1[img].x << 20) | ((unsigned)b << 8) | 128u;
    med[img] = funmap_u(u) + 0.2f;
  }
}

// ==== MFMA row pass: t1T[img][n][h] = bf16( sum_k padded[r][k] * Cm[n][k] ) ====
// A = single bf16 (hi), B = split hi/lo -> 2 MFMAs per fragment pair
__global__ __launch_bounds__(256, 3) void k_rowpass(
    const float* __restrict__ x, const float* __restrict__ mask,
    const float* __restrict__ med,
    const unsigned short* __restrict__ CmH, const unsigned short* __restrict__ CmL,
    unsigned short* __restrict__ t1h)
{
  __shared__ __align__(16) unsigned short AsH[128][40];
  __shared__ __align__(16) unsigned short BsH[128][40];
  __shared__ __align__(16) unsigned short BsL[128][40];

  // XCD swizzle: 4 sibling n-blocks (same rows) on the same XCD
  const int b    = blockIdx.x;           // 0..1535
  const int xcd  = b & 7;
  const int i8   = b >> 3;               // 0..191
  const int rblk = xcd * 48 + (i8 >> 2); // 0..383
  const int nblk = i8 & 3;
  const int r0 = rblk * 128;
  const int n0 = nblk * 128;
  const int bc = r0 >> 9;
  const int bb = bc / 3;
  const float mv = med[bc];

  const int t    = threadIdx.x;
  const int lane = t & 63;
  const int wv   = t >> 6;
  const int wm   = (wv >> 1) * 64;
  const int wn   = (wv & 1) * 64;
  const int fr   = lane & 15;
  const int fg   = lane >> 4;

  f32x4 acc[4][4];
  #pragma unroll
  for(int i = 0; i < 4; i++)
    #pragma unroll
    for(int j = 0; j < 4; j++) acc[i][j] = (f32x4){0.f, 0.f, 0.f, 0.f};

  const int sm = t >> 1;             // staging row 0..127
  const int kc = (t & 1) << 4;       // 0 or 16

  for(int k0 = 0; k0 < 512; k0 += 32){
    // --- stage A: median-padded x as single bf16 (16 ushorts/thread) ---
    {
      const float* xr = x    + ((size_t)(r0 + sm) << 9) + k0 + kc;
      const float* mr = mask + (size_t)bb * HW + ((size_t)((r0 + sm) & 511) << 9) + k0 + kc;
      unsigned hp[8];
      #pragma unroll
      for(int q = 0; q < 4; q++){
        float4 xv = *(const float4*)(xr + q * 4);
        float4 mk = *(const float4*)(mr + q * 4);
        unsigned h0 = bf16rne((mk.x != 0.f) ? xv.x : mv);
        unsigned h1 = bf16rne((mk.y != 0.f) ? xv.y : mv);
        unsigned h2 = bf16rne((mk.z != 0.f) ? xv.z : mv);
        unsigned h3 = bf16rne((mk.w != 0.f) ? xv.w : mv);
        hp[q*2]   = (h1 << 16) | h0;
        hp[q*2+1] = (h3 << 16) | h2;
      }
      *(uint4*)&AsH[sm][kc]     = make_uint4(hp[0], hp[1], hp[2], hp[3]);
      *(uint4*)&AsH[sm][kc + 8] = make_uint4(hp[4], hp[5], hp[6], hp[7]);
    }
    // --- stage B: circulant tile (16 ushorts/thread = 2x uint4) ---
    {
      const size_t gofs = ((size_t)(n0 + sm) << 9) + k0 + kc;
      *(uint4*)&BsH[sm][kc]     = *(const uint4*)(CmH + gofs);
      *(uint4*)&BsH[sm][kc + 8] = *(const uint4*)(CmH + gofs + 8);
      *(uint4*)&BsL[sm][kc]     = *(const uint4*)(CmL + gofs);
      *(uint4*)&BsL[sm][kc + 8] = *(const uint4*)(CmL + gofs + 8);
    }
    __syncthreads();

    bf16x8 ah[4], bh[4], bl[4];
    #pragma unroll
    for(int i = 0; i < 4; i++)
      ah[i] = *(const bf16x8*)&AsH[wm + i*16 + fr][fg*8];
    #pragma unroll
    for(int j = 0; j < 4; j++){
      bh[j] = *(const bf16x8*)&BsH[wn + j*16 + fr][fg*8];
      bl[j] = *(const bf16x8*)&BsL[wn + j*16 + fr][fg*8];
    }
    #pragma unroll
    for(int i = 0; i < 4; i++)
      #pragma unroll
      for(int j = 0; j < 4; j++){
        acc[i][j] = __builtin_amdgcn_mfma_f32_16x16x32_bf16(ah[i], bh[j], acc[i][j], 0, 0, 0);
        acc[i][j] = __builtin_amdgcn_mfma_f32_16x16x32_bf16(ah[i], bl[j], acc[i][j], 0, 0, 0);
      }
    __syncthreads();
  }

  // --- store t1 transposed as single bf16: t1T[img][n][h] ---
  const int img = r0 >> 9;
  const int hb  = r0 & 511;
  #pragma unroll
  for(int i = 0; i < 4; i++)
    #pragma unroll
    for(int j = 0; j < 4; j++){
      f32x4 a = acc[i][j];
      unsigned b0 = bf16rne(a[0]), b1 = bf16rne(a[1]), b2 = bf16rne(a[2]), b3 = bf16rne(a[3]);
      int n = n0 + wn + j*16 + fr;
      int h = hb + wm + i*16 + fg*4;
      *(uint2*)&t1h[(size_t)img * HW + ((size_t)n << 9) + h] =
          make_uint2((b1<<16)|b0, (b3<<16)|b2);
    }
}

// ==== MFMA col pass + fused q-histogram ====
// res[img][h'][w] = | sum_h Cm[h'][h] * t1T[img][w][h] | ; qh[img] += hist(trunc(res*256))
__global__ __launch_bounds__(256, 3) void k_colpass(
    const unsigned short* __restrict__ t1h,
    const unsigned short* __restrict__ CmH, const unsigned short* __restrict__ CmL,
    float* __restrict__ res, unsigned* __restrict__ qh)
{
  __shared__ __align__(16) unsigned short SH[3 * 128 * 40];   // 30720 B
  unsigned short (*AsH)[40] = (unsigned short(*)[40])SH;
  unsigned short (*AsL)[40] = (unsigned short(*)[40])(SH + 128 * 40);
  unsigned short (*Bs)[40]  = (unsigned short(*)[40])(SH + 2 * 128 * 40);

  // XCD swizzle: all 16 blocks of one image on the same XCD (t1 image L2-resident)
  const int b    = blockIdx.x;           // 0..1535
  const int xcd  = b & 7;
  const int i8   = b >> 3;               // 0..191
  const int img  = xcd * 12 + (i8 >> 4);
  const int r16  = i8 & 15;
  const int hp0  = (r16 >> 2) * 128;
  const int w0   = (r16 & 3) * 128;

  const int t    = threadIdx.x;
  const int lane = t & 63;
  const int wv   = t >> 6;
  const int wm   = (wv >> 1) * 64;
  const int wn   = (wv & 1) * 64;
  const int fr   = lane & 15;
  const int fg   = lane >> 4;

  f32x4 acc[4][4];
  #pragma unroll
  for(int i = 0; i < 4; i++)
    #pragma unroll
    for(int j = 0; j < 4; j++) acc[i][j] = (f32x4){0.f, 0.f, 0.f, 0.f};

  const int sm = t >> 1;
  const int kc = (t & 1) << 4;

  for(int k0 = 0; k0 < 512; k0 += 32){
    // --- stage A: circulant tile rows hp0+m (16 ushorts/thread) ---
    {
      const size_t gofs = ((size_t)(hp0 + sm) << 9) + k0 + kc;
      *(uint4*)&AsH[sm][kc]     = *(const uint4*)(CmH + gofs);
      *(uint4*)&AsH[sm][kc + 8] = *(const uint4*)(CmH + gofs + 8);
      *(uint4*)&AsL[sm][kc]     = *(const uint4*)(CmL + gofs);
      *(uint4*)&AsL[sm][kc + 8] = *(const uint4*)(CmL + gofs + 8);
    }
    // --- stage B: t1T tile, contiguous along h (16 ushorts/thread) ---
    {
      const size_t gofs = (size_t)img * HW + ((size_t)(w0 + sm) << 9) + k0 + kc;
      *(uint4*)&Bs[sm][kc]     = *(const uint4*)(t1h + gofs);
      *(uint4*)&Bs[sm][kc + 8] = *(const uint4*)(t1h + gofs + 8);
    }
    __syncthreads();

    bf16x8 ah[4], al[4], bv[4];
    #pragma unroll
    for(int i = 0; i < 4; i++){
      ah[i] = *(const bf16x8*)&AsH[wm + i*16 + fr][fg*8];
      al[i] = *(const bf16x8*)&AsL[wm + i*16 + fr][fg*8];
    }
    #pragma unroll
    for(int j = 0; j < 4; j++)
      bv[j] = *(const bf16x8*)&Bs[wn + j*16 + fr][fg*8];

    #pragma unroll
    for(int i = 0; i < 4; i++)
      #pragma unroll
      for(int j = 0; j < 4; j++){
        acc[i][j] = __builtin_amdgcn_mfma_f32_16x16x32_bf16(ah[i], bv[j], acc[i][j], 0, 0, 0);
        acc[i][j] = __builtin_amdgcn_mfma_f32_16x16x32_bf16(al[i], bv[j], acc[i][j], 0, 0, 0);
      }
    __syncthreads();
  }

  // --- epilogue: store |acc| and histogram it in LDS (reuse tile buffer) ---
  unsigned* shh = (unsigned*)SH;          // 4096 bins = 16 KB <= 30720 B
  for(int i = t; i < NQBIN; i += 256) shh[i] = 0;
  __syncthreads();

  float* rimg = res + (size_t)img * HW;
  #pragma unroll
  for(int i = 0; i < 4; i++)
    #pragma unroll
    for(int j = 0; j < 4; j++){
      f32x4 a = acc[i][j];
      int w  = w0 + wn + j*16 + fr;
      int hp = hp0 + wm + i*16 + fg*4;
      #pragma unroll
      for(int r = 0; r < 4; r++){
        float v = fabsf(a[r]);
        rimg[((size_t)(hp + r) << 9) + w] = v;
        atomicAdd(&shh[min((int)(v * 256.f), NQBIN - 1)], 1u);
      }
    }
  __syncthreads();

  unsigned* hg = qh + (size_t)img * NQBIN;
  for(int i = t; i < NQBIN; i += 256){
    unsigned c = shh[i];
    if(c) atomicAdd(&hg[i], c);
  }
}

// ---- percentiles (linear interp at 3% / 97%) -> (lo, 1/(hi-lo)) ----
__global__ void k_pct(const unsigned* __restrict__ qh, float2* __restrict__ prm){
  int img = blockIdx.x, t = threadIdx.x;
  const unsigned* h = qh + (size_t)img * NQBIN;
  __shared__ unsigned sh[NQBIN];
  for(int i = t; i < NQBIN; i += 256) sh[i] = h[i];
  __syncthreads();
  if(t == 0){
    const unsigned targ[4] = {7864u, 7865u, 254278u, 254279u};
    float v[4]; unsigned cum = 0; int b = 0;
    for(int q = 0; q < 4; q++){
      while(cum + sh[b] <= targ[q]){ cum += sh[b]; ++b; }
      v[q] = (float)b * (1.0f / 256.0f);
    }
    double plo = 0.03 * 262143.0;
    double phi = 0.97 * 262143.0;
    float lo = v[0] + (float)(plo - 7864.0)   * (v[1] - v[0]);
    float hi = v[2] + (float)(phi - 254278.0) * (v[3] - v[2]);
    prm[img] = make_float2(lo, 1.0f / (hi - lo));
  }
}

// ---- in-place normalize: out = (res - lo) * inv * mask ----
__global__ __launch_bounds__(256) void k_norm(float* __restrict__ out, const float* __restrict__ mask,
                                              const float2* __restrict__ prm){
  size_t i4 = (size_t)blockIdx.x * blockDim.x + threadIdx.x;
  const size_t total4 = (size_t)NIMG * HW / 4;
  const size_t step = (size_t)gridDim.x * blockDim.x;
  for(; i4 < total4; i4 += step){
    size_t i = i4 * 4;
    int bc = (int)(i >> 18);
    int bb = bc / 3;
    size_t mi = ((size_t)bb << 18) + (i & 0x3FFFFu);
    float4 r = *(float4*)(out + i);
    float4 m = *(const float4*)(mask + mi);
    float2 p = prm[bc];
    float4 o;
    o.x = (r.x - p.x) * p.y * m.x;
    o.y = (r.y - p.x) * p.y * m.y;
    o.z = (r.z - p.x) * p.y * m.z;
    o.w = (r.w - p.x) * p.y * m.w;
    *(float4*)(out + i) = o;
  }
}

extern "C" void kernel_launch(void* const* d_in, const int* in_sizes, int n_in,
                              void* d_out, int out_size, void* d_ws, size_t ws_size,
                              hipStream_t stream)
{
  const float* x       = (const float*)d_in[0];
  const float* mask    = (const float*)d_in[1];
  const float* fmap_in = (const float*)d_in[2];
  float* out = (float*)d_out;

  const size_t T1_BYTES = (size_t)NIMG * HW * 2;   // 50,331,648 (bf16 t1T)
  char* ws = (char*)d_ws;
  unsigned short* t1h = (unsigned short*)ws;        // lives rowpass..colpass
  // radix histograms alias the (not-yet-written) t1 region:
  unsigned* h1 = (unsigned*)ws;                                        // 1.5 MB
  unsigned* h2 = (unsigned*)(ws + (size_t)NIMG * 4096 * 4);            // 1.5 MB
  char* tail = ws + T1_BYTES;
  float*          Dir = (float*)tail;                                  // 2048 B
  unsigned short* CmH = (unsigned short*)(tail + 2048);                // 512 KB
  unsigned short* CmL = (unsigned short*)(tail + 2048 + 524288);       // 512 KB
  char* tail2 = tail + 2048 + 1048576;
  float*  med  = (float*)tail2;                     // 512 B slot
  uint2*  sel1 = (uint2*)(tail2 + 512);             // 768 B
  float2* prm  = (float2*)(tail2 + 1536);           // 768 B
  unsigned* qh = (unsigned*)(tail2 + 2560);         // 96*4096*4 = 1.5 MB (NOT aliased with t1h)

  k_dir<<<512, 256, 0, stream>>>(fmap_in, Dir);
  k_cmat<<<512, 256, 0, stream>>>(Dir, CmH, CmL);

  // 2-pass LDS radix select: median prefix to 24 bits (midpoint, err <= 8e-6)
  hipMemsetAsync(h1, 0, (size_t)NIMG * 4096 * 4 * 2, stream);
  k_p1<<<NIMG * 8, 256, 0, stream>>>(x, h1);
  k_scan1<<<NIMG, 256, 0, stream>>>(h1, sel1);
  k_p2<<<NIMG * 8, 256, 0, stream>>>(x, sel1, h2);
  k_scan_med<<<NIMG, 256, 0, stream>>>(h2, sel1, med);

  hipMemsetAsync(qh, 0, (size_t)NIMG * NQBIN * 4, stream);
  k_rowpass<<<1536, 256, 0, stream>>>(x, mask, med, CmH, CmL, t1h);
  k_colpass<<<1536, 256, 0, stream>>>(t1h, CmH, CmL, out, qh);

  k_pct<<<NIMG, 256, 0, stream>>>(qh, prm);
  k_norm<<<2048, 256, 0, stream>>>(out, mask, prm);
}